// Round 3
// baseline (552.825 us; speedup 1.0000x reference)
//
#include <hip/hip_runtime.h>

constexpr int BLOCK = 1024;
constexpr int B_   = 4;
constexpr int C_   = 64;      // feature channels
constexpr int N_   = 32768;
constexpr int K_   = 16;      // neighbor dim in memory
constexpr int CIN  = 68;      // 64 feat + 3 diff + 1 dist
constexpr int C1   = 128;
constexpr int C2   = 64;
constexpr int C3   = 64;
constexpr int P_   = 32;      // points per block
constexpr int NCOL = 96;      // 3 * P_

// ---------------- generic register-tiled layer: out = relu(Wt^T in + b) ----
// in:  LDS [CI][NCOL], wt: LDS [CI][CO] (BN-folded), bf: LDS [CO]
// each thread computes a COT x COLT tile of the [CO][NCOL] output.
template<int CI, int CO, int COT, int COLT>
__device__ __forceinline__ void mlp_layer(const float* __restrict__ in,
                                          const float* __restrict__ wt,
                                          const float* __restrict__ bf,
                                          float* __restrict__ outb, int tid)
{
    constexpr int NXT = NCOL / COLT;
    static_assert((CO / COT) * NXT == BLOCK, "tile grid must equal block");
    const int tx = tid % NXT;
    const int ty = tid / NXT;
    const int co0  = ty * COT;
    const int col0 = tx * COLT;

    float acc[COT][COLT];
#pragma unroll
    for (int j = 0; j < COT; ++j)
#pragma unroll
        for (int c = 0; c < COLT; ++c) acc[j][c] = 0.0f;

#pragma unroll 2
    for (int ci = 0; ci < CI; ++ci) {
        float w[COT], x[COLT];
#pragma unroll
        for (int j = 0; j < COT; ++j) w[j] = wt[ci * CO + co0 + j];
#pragma unroll
        for (int c = 0; c < COLT; ++c) x[c] = in[ci * NCOL + col0 + c];
#pragma unroll
        for (int j = 0; j < COT; ++j)
#pragma unroll
            for (int c = 0; c < COLT; ++c)
                acc[j][c] = fmaf(w[j], x[c], acc[j][c]);
    }
#pragma unroll
    for (int j = 0; j < COT; ++j) {
        const float bb = bf[co0 + j];
#pragma unroll
        for (int c = 0; c < COLT; ++c)
            outb[(co0 + j) * NCOL + col0 + c] = fmaxf(acc[j][c] + bb, 0.0f);
    }
}

__global__ __launch_bounds__(BLOCK, 1)
void mvp_fused(const float* __restrict__ src, const float* __restrict__ tgt,
               const float* __restrict__ feat,
               const float* __restrict__ W1, const float* __restrict__ b1,
               const float* __restrict__ g1, const float* __restrict__ be1,
               const float* __restrict__ W2, const float* __restrict__ b2,
               const float* __restrict__ g2, const float* __restrict__ be2,
               const float* __restrict__ W3, const float* __restrict__ b3,
               const float* __restrict__ g3, const float* __restrict__ be3,
               float* __restrict__ out)
{
    __shared__ float w1t[CIN * C1];   // [ci][co], BN-folded
    __shared__ float w2t[C1 * C2];
    __shared__ float w3t[C2 * C3];
    __shared__ float bf1[C1], bf2[C2], bf3[C3];
    __shared__ float bufA[CIN * NCOL];  // x, then h2
    __shared__ float bufB[C1 * NCOL];   // h1

    const int tid = threadIdx.x;
    const int b   = blockIdx.x >> 10;            // N_/P_ = 1024 blocks per batch
    const int n0  = (blockIdx.x & 1023) * P_;
    const float RS = rsqrtf(1.0f + 1e-5f);

    // ---- stage BN-folded transposed weights into LDS ----
    for (int idx = tid; idx < CIN * C1; idx += BLOCK) {
        const int ci = idx >> 7, co = idx & 127;
        w1t[idx] = W1[co * CIN + ci] * (g1[co] * RS);
    }
    for (int idx = tid; idx < C1 * C2; idx += BLOCK) {
        const int ci = idx >> 6, co = idx & 63;
        w2t[idx] = W2[co * C1 + ci] * (g2[co] * RS);
    }
    for (int idx = tid; idx < C2 * C3; idx += BLOCK) {
        const int ci = idx >> 6, co = idx & 63;
        w3t[idx] = W3[co * C2 + ci] * (g3[co] * RS);
    }
    if (tid < C1) bf1[tid] = b1[tid] * (g1[tid] * RS) + be1[tid];
    else if (tid >= 128 && tid < 128 + C2) { int t = tid - 128; bf2[t] = b2[t] * (g2[t] * RS) + be2[t]; }
    else if (tid >= 256 && tid < 256 + C3) { int t = tid - 256; bf3[t] = b3[t] * (g3[t] * RS) + be3[t]; }

    // ---- stage input columns: x = [feature(:, :3); diff_xyz; dist] ----
    // feature rows are 16 floats; we need k=0..2 -> one aligned float4 load.
    for (int idx = tid; idx < C_ * P_; idx += BLOCK) {
        const int c = idx >> 5, lp = idx & 31;
        const float4 f = *reinterpret_cast<const float4*>(
            feat + ((size_t)(b * C_ + c) * N_ + (n0 + lp)) * K_);
        float* dst = bufA + c * NCOL + lp * 3;
        dst[0] = f.x; dst[1] = f.y; dst[2] = f.z;
    }
    if (tid >= 512 && tid < 512 + NCOL) {
        const int t = tid - 512;
        const int lp = t / 3, k = t % 3;
        const int n = n0 + lp;
        const float dx = src[((size_t)(b * 3 + 0) * N_ + n) * K_ + k]
                       - tgt[(size_t)(b * 3 + 0) * N_ + n];
        const float dy = src[((size_t)(b * 3 + 1) * N_ + n) * K_ + k]
                       - tgt[(size_t)(b * 3 + 1) * N_ + n];
        const float dz = src[((size_t)(b * 3 + 2) * N_ + n) * K_ + k]
                       - tgt[(size_t)(b * 3 + 2) * N_ + n];
        bufA[(C_ + 0) * NCOL + t] = dx;
        bufA[(C_ + 1) * NCOL + t] = dy;
        bufA[(C_ + 2) * NCOL + t] = dz;
        bufA[(C_ + 3) * NCOL + t] = dx * dx + dy * dy + dz * dz;
    }
    __syncthreads();

    // ---- layer 1: 68 -> 128 (each thread: 2 co x 6 cols) ----
    mlp_layer<CIN, C1, 2, 6>(bufA, w1t, bf1, bufB, tid);
    __syncthreads();

    // ---- layer 2: 128 -> 64 (each thread: 2 co x 3 cols) ----
    mlp_layer<C1, C2, 2, 3>(bufB, w2t, bf2, bufA, tid);
    __syncthreads();

    // ---- layer 3: 64 -> 64, fused relu + neighbor-sum + store ----
    // each thread: 2 co x 1 point (3 neighbor cols)
    {
        constexpr int COT = 2, COLT = 3, NXT = NCOL / COLT;  // NXT = 32
        const int tx = tid % NXT;         // point index within block
        const int ty = tid / NXT;
        const int co0  = ty * COT;
        const int col0 = tx * COLT;

        float acc[COT][COLT];
#pragma unroll
        for (int j = 0; j < COT; ++j)
#pragma unroll
            for (int c = 0; c < COLT; ++c) acc[j][c] = 0.0f;

#pragma unroll 2
        for (int ci = 0; ci < C2; ++ci) {
            float w[COT], x[COLT];
#pragma unroll
            for (int j = 0; j < COT; ++j) w[j] = w3t[ci * C3 + co0 + j];
#pragma unroll
            for (int c = 0; c < COLT; ++c) x[c] = bufA[ci * NCOL + col0 + c];
#pragma unroll
            for (int j = 0; j < COT; ++j)
#pragma unroll
                for (int c = 0; c < COLT; ++c)
                    acc[j][c] = fmaf(w[j], x[c], acc[j][c]);
        }

#pragma unroll
        for (int j = 0; j < COT; ++j) {
            const float bb = bf3[co0 + j];
            const float s = fmaxf(acc[j][0] + bb, 0.f)
                          + fmaxf(acc[j][1] + bb, 0.f)
                          + fmaxf(acc[j][2] + bb, 0.f);
            out[(size_t)(b * C3 + co0 + j) * N_ + n0 + tx] = s;
        }
    }
}

extern "C" void kernel_launch(void* const* d_in, const int* in_sizes, int n_in,
                              void* d_out, int out_size, void* d_ws, size_t ws_size,
                              hipStream_t stream) {
    const float* src  = (const float*)d_in[0];
    const float* tgt  = (const float*)d_in[1];
    const float* feat = (const float*)d_in[2];
    const float* W1 = (const float*)d_in[3];
    const float* b1 = (const float*)d_in[4];
    const float* g1 = (const float*)d_in[5];
    const float* be1= (const float*)d_in[6];
    const float* W2 = (const float*)d_in[7];
    const float* b2 = (const float*)d_in[8];
    const float* g2 = (const float*)d_in[9];
    const float* be2= (const float*)d_in[10];
    const float* W3 = (const float*)d_in[11];
    const float* b3 = (const float*)d_in[12];
    const float* g3 = (const float*)d_in[13];
    const float* be3= (const float*)d_in[14];
    float* out = (float*)d_out;

    const int grid = B_ * (N_ / P_);  // 4096
    mvp_fused<<<grid, BLOCK, 0, stream>>>(src, tgt, feat,
                                          W1, b1, g1, be1,
                                          W2, b2, g2, be2,
                                          W3, b3, g3, be3, out);
}

// Round 4
// 268.777 us; speedup vs baseline: 2.0568x; 2.0568x over previous
//
#include <hip/hip_runtime.h>
#include <math.h>

typedef __attribute__((ext_vector_type(8))) short short8;
typedef __attribute__((ext_vector_type(4))) short short4v;
typedef __attribute__((ext_vector_type(4))) float f32x4;

constexpr int BLOCK = 1024;
constexpr int B_ = 4, C_ = 64, N_ = 32768, K_ = 16;
constexpr int P_ = 32;            // points per block -> 96 cols (col = k*32 + p)
// LDS row strides in bf16 elements (16B-aligned rows, odd/16 multiples to spread banks)
constexpr int XS  = 104;          // xa rows: ci 0..67 valid, 68..95 zero-padded (frag reads k<=95)
constexpr int H1S = 136;          // h1 rows: 128 co
constexpr int H2S = 72;           // h2 rows: 64 co

// round-to-nearest-even split: f = hi_bf16 + lo_bf16 (+O(2^-17 rel))
__device__ __forceinline__ void bf16split(float f, short &hi, short &lo) {
    unsigned u  = __builtin_bit_cast(unsigned, f);
    unsigned hb = (u + 0x7FFFu + ((u >> 16) & 1u)) & 0xFFFF0000u;
    float hf    = __builtin_bit_cast(float, hb);
    hi = (short)(hb >> 16);
    float lf    = f - hf;                       // exact
    unsigned ul = __builtin_bit_cast(unsigned, lf);
    lo = (short)((ul + 0x7FFFu + ((ul >> 16) & 1u)) >> 16);
}

// gather A-fragment: 8 f32 of W[co][kb..kb+7] from global, fold BN scale, hi/lo split.
// Lanes with k >= CIv get zeros (exec-masked loads, no OOB).
__device__ __forceinline__ void load_wfrag(const float* __restrict__ W, int CI, int CIv,
                                           int co, int kb, float gs, short8 &h8, short8 &l8) {
    float wv[8];
#pragma unroll
    for (int j = 0; j < 8; j += 4) {
        const int k = kb + j;
        if (k + 4 <= CIv) {
            const float4 q = *reinterpret_cast<const float4*>(W + (size_t)co * CI + k);
            wv[j] = q.x; wv[j+1] = q.y; wv[j+2] = q.z; wv[j+3] = q.w;
        } else {
#pragma unroll
            for (int t = 0; t < 4; ++t)
                wv[j+t] = (k + t < CIv) ? W[(size_t)co * CI + k + t] : 0.0f;
        }
    }
#pragma unroll
    for (int j = 0; j < 8; ++j) {
        short hi, lo; bf16split(wv[j] * gs, hi, lo);
        h8[j] = hi; l8[j] = lo;
    }
}

__device__ __forceinline__ f32x4 mm(short8 a, short8 b, f32x4 c) {
    return __builtin_amdgcn_mfma_f32_16x16x32_bf16(a, b, c, 0, 0, 0);
}

__global__ __launch_bounds__(BLOCK, 4)
void mvp_mfma(const float* __restrict__ src, const float* __restrict__ tgt,
              const float* __restrict__ feat,
              const float* __restrict__ W1, const float* __restrict__ b1,
              const float* __restrict__ g1, const float* __restrict__ be1,
              const float* __restrict__ W2, const float* __restrict__ b2,
              const float* __restrict__ g2, const float* __restrict__ be2,
              const float* __restrict__ W3, const float* __restrict__ b3,
              const float* __restrict__ g3, const float* __restrict__ be3,
              float* __restrict__ out)
{
    __shared__ __align__(16) unsigned short xa_hi[96*XS],  xa_lo[96*XS];   // 20.0 KB x2
    __shared__ __align__(16) unsigned short h1_hi[96*H1S], h1_lo[96*H1S];  // 26.1 KB x2
    __shared__ __align__(16) unsigned short h2_hi[96*H2S], h2_lo[96*H2S];  // 13.8 KB x2
    __shared__ float bias1[128], bias2[64], bias3[64];

    const int tid = threadIdx.x;
    const int w   = tid >> 6;
    const int l   = tid & 63;
    const int b   = blockIdx.x >> 10;
    const int n0  = (blockIdx.x & 1023) * P_;
    const float RS = 1.0f / sqrtf(1.0f + 1e-5f);

    // ================= staging =================
    // zero xa pad region ci 68..99 (frag k-range reaches 95)
    for (int idx = tid; idx < 96 * 8; idx += BLOCK) {
        const int col = idx >> 3, ch = idx & 7;
        *reinterpret_cast<short4v*>(&xa_hi[col*XS + 68 + ch*4]) = short4v{0,0,0,0};
        *reinterpret_cast<short4v*>(&xa_lo[col*XS + 68 + ch*4]) = short4v{0,0,0,0};
    }
    // feature -> ci 0..63 (one aligned float4 per row covers k=0..2)
    for (int idx = tid; idx < C_ * P_; idx += BLOCK) {
        const int c = idx >> 5, p = idx & 31;
        const float4 f = *reinterpret_cast<const float4*>(
            feat + ((size_t)(b*C_ + c) * N_ + (n0 + p)) * K_);
        const float v[3] = {f.x, f.y, f.z};
#pragma unroll
        for (int k = 0; k < 3; ++k) {
            short hi, lo; bf16split(v[k], hi, lo);
            const int off = (k*32 + p) * XS + c;
            xa_hi[off] = (unsigned short)hi; xa_lo[off] = (unsigned short)lo;
        }
    }
    // relation features -> ci 64..67
    if (tid < 96) {
        const int p = tid & 31, k = tid >> 5;
        const int n = n0 + p;
        float d[4];
        d[0] = src[((size_t)(b*3+0)*N_ + n)*K_ + k] - tgt[(size_t)(b*3+0)*N_ + n];
        d[1] = src[((size_t)(b*3+1)*N_ + n)*K_ + k] - tgt[(size_t)(b*3+1)*N_ + n];
        d[2] = src[((size_t)(b*3+2)*N_ + n)*K_ + k] - tgt[(size_t)(b*3+2)*N_ + n];
        d[3] = d[0]*d[0] + d[1]*d[1] + d[2]*d[2];
        const int col = k*32 + p;
#pragma unroll
        for (int j = 0; j < 4; ++j) {
            short hi, lo; bf16split(d[j], hi, lo);
            xa_hi[col*XS + 64 + j] = (unsigned short)hi;
            xa_lo[col*XS + 64 + j] = (unsigned short)lo;
        }
    }
    // folded biases: g*RS*b + be
    if (tid >= 256 && tid < 384) { int c = tid - 256; bias1[c] = b1[c]*(g1[c]*RS) + be1[c]; }
    if (tid >= 384 && tid < 448) { int c = tid - 384; bias2[c] = b2[c]*(g2[c]*RS) + be2[c]; }
    if (tid >= 448 && tid < 512) { int c = tid - 448; bias3[c] = b3[c]*(g3[c]*RS) + be3[c]; }
    __syncthreads();

    const int kq  = (l >> 4) << 3;   // fragment k-offset: 0,8,16,24
    const int lr  = l & 15;          // row/col within 16-tile
    const int rq  = (l >> 4) << 2;   // C/D row offset

    // ================= L1: 68 -> 128 =================
    {
        const int m = w >> 1, hh = w & 1;          // 8 M-tiles x 2 point-halves
        const int co = m*16 + lr;
        const float gs = g1[co] * RS;
        short8 ah[3], al[3];
#pragma unroll
        for (int ks = 0; ks < 3; ++ks)
            load_wfrag(W1, 68, 68, co, ks*32 + kq, gs, ah[ks], al[ks]);
        f32x4 acc[3] = {f32x4{0,0,0,0}, f32x4{0,0,0,0}, f32x4{0,0,0,0}};
#pragma unroll
        for (int ks = 0; ks < 3; ++ks) {
#pragma unroll
            for (int t = 0; t < 3; ++t) {          // N-tiles {hh, hh+2, hh+4}
                const int col = (2*t + hh)*16 + lr;
                const short8 bh = *reinterpret_cast<const short8*>(&xa_hi[col*XS + ks*32 + kq]);
                const short8 bl = *reinterpret_cast<const short8*>(&xa_lo[col*XS + ks*32 + kq]);
                acc[t] = mm(ah[ks], bh, acc[t]);
                acc[t] = mm(al[ks], bh, acc[t]);
                acc[t] = mm(ah[ks], bl, acc[t]);
            }
        }
        const int co0 = m*16 + rq;
        const float4 bb = *reinterpret_cast<const float4*>(&bias1[co0]);
        const float bbv[4] = {bb.x, bb.y, bb.z, bb.w};
#pragma unroll
        for (int t = 0; t < 3; ++t) {
            const int col = (2*t + hh)*16 + lr;
            short4v h4, l4;
#pragma unroll
            for (int r = 0; r < 4; ++r) {
                const float v = fmaxf(acc[t][r] + bbv[r], 0.0f);
                short hi, lo; bf16split(v, hi, lo);
                h4[r] = hi; l4[r] = lo;
            }
            *reinterpret_cast<short4v*>(&h1_hi[col*H1S + co0]) = h4;
            *reinterpret_cast<short4v*>(&h1_lo[col*H1S + co0]) = l4;
        }
    }
    __syncthreads();

    // ================= L2: 128 -> 64 =================
    {
        const int ntile = (w < 8) ? 2 : 1;         // 24 tiles over 16 waves
        for (int tt = 0; tt < ntile; ++tt) {
            const int t = w + tt*16;               // 0..23
            const int m = t / 6, n = t % 6;
            const int co = m*16 + lr;
            const float gs = g2[co] * RS;
            const int col = n*16 + lr;
            f32x4 acc = {0,0,0,0};
#pragma unroll
            for (int ks = 0; ks < 4; ++ks) {
                short8 ah, al;
                load_wfrag(W2, 128, 128, co, ks*32 + kq, gs, ah, al);
                const short8 bh = *reinterpret_cast<const short8*>(&h1_hi[col*H1S + ks*32 + kq]);
                const short8 bl = *reinterpret_cast<const short8*>(&h1_lo[col*H1S + ks*32 + kq]);
                acc = mm(ah, bh, acc);
                acc = mm(al, bh, acc);
                acc = mm(ah, bl, acc);
            }
            const int co0 = m*16 + rq;
            const float4 bb = *reinterpret_cast<const float4*>(&bias2[co0]);
            const float bbv[4] = {bb.x, bb.y, bb.z, bb.w};
            short4v h4, l4;
#pragma unroll
            for (int r = 0; r < 4; ++r) {
                const float v = fmaxf(acc[r] + bbv[r], 0.0f);
                short hi, lo; bf16split(v, hi, lo);
                h4[r] = hi; l4[r] = lo;
            }
            *reinterpret_cast<short4v*>(&h2_hi[col*H2S + co0]) = h4;
            *reinterpret_cast<short4v*>(&h2_lo[col*H2S + co0]) = l4;
        }
    }
    __syncthreads();

    // ================= L3: 64 -> 64, relu + neighbor-sum + store =================
    if (w < 8) {
        const int m = w >> 1, hh = w & 1;          // 4 M-tiles x 2 point-halves
        const int co = m*16 + lr;
        const float gs = g3[co] * RS;
        short8 ah[2], al[2];
#pragma unroll
        for (int ks = 0; ks < 2; ++ks)
            load_wfrag(W3, 64, 64, co, ks*32 + kq, gs, ah[ks], al[ks]);
        f32x4 acc[3] = {f32x4{0,0,0,0}, f32x4{0,0,0,0}, f32x4{0,0,0,0}};
#pragma unroll
        for (int ks = 0; ks < 2; ++ks) {
#pragma unroll
            for (int t = 0; t < 3; ++t) {          // t = neighbor k; col = k*32 + p
                const int col = t*32 + hh*16 + lr;
                const short8 bh = *reinterpret_cast<const short8*>(&h2_hi[col*H2S + ks*32 + kq]);
                const short8 bl = *reinterpret_cast<const short8*>(&h2_lo[col*H2S + ks*32 + kq]);
                acc[t] = mm(ah[ks], bh, acc[t]);
                acc[t] = mm(al[ks], bh, acc[t]);
                acc[t] = mm(ah[ks], bl, acc[t]);
            }
        }
        const int co0 = m*16 + rq;
        const float4 bb = *reinterpret_cast<const float4*>(&bias3[co0]);
        const float bbv[4] = {bb.x, bb.y, bb.z, bb.w};
        const int p = hh*16 + lr;
#pragma unroll
        for (int r = 0; r < 4; ++r) {
            float s = 0.0f;
#pragma unroll
            for (int t = 0; t < 3; ++t) s += fmaxf(acc[t][r] + bbv[r], 0.0f);
            out[(size_t)(b*64 + co0 + r) * N_ + n0 + p] = s;
        }
    }
}

extern "C" void kernel_launch(void* const* d_in, const int* in_sizes, int n_in,
                              void* d_out, int out_size, void* d_ws, size_t ws_size,
                              hipStream_t stream) {
    const float* src  = (const float*)d_in[0];
    const float* tgt  = (const float*)d_in[1];
    const float* feat = (const float*)d_in[2];
    const float* W1 = (const float*)d_in[3];
    const float* b1 = (const float*)d_in[4];
    const float* g1 = (const float*)d_in[5];
    const float* be1= (const float*)d_in[6];
    const float* W2 = (const float*)d_in[7];
    const float* b2 = (const float*)d_in[8];
    const float* g2 = (const float*)d_in[9];
    const float* be2= (const float*)d_in[10];
    const float* W3 = (const float*)d_in[11];
    const float* b3 = (const float*)d_in[12];
    const float* g3 = (const float*)d_in[13];
    const float* be3= (const float*)d_in[14];
    float* out = (float*)d_out;

    const int grid = B_ * (N_ / P_);  // 4096
    mvp_mfma<<<grid, BLOCK, 0, stream>>>(src, tgt, feat,
                                         W1, b1, g1, be1,
                                         W2, b2, g2, be2,
                                         W3, b3, g3, be3, out);
}

// Round 5
// 189.694 us; speedup vs baseline: 2.9143x; 1.4169x over previous
//
#include <hip/hip_runtime.h>
#include <math.h>

typedef __attribute__((ext_vector_type(8))) short short8;
typedef __attribute__((ext_vector_type(4))) short short4v;
typedef __attribute__((ext_vector_type(4))) float f32x4;

constexpr int BLOCK = 1024;
constexpr int B_ = 4, C_ = 64, N_ = 32768, K_ = 16;
constexpr int P_ = 32;            // points per block -> 96 cols (col = k*32 + p)
// LDS row strides in bf16 elements (16B-aligned rows)
constexpr int XS  = 104;          // xa rows: ci 0..67 valid, 68..95 zero-padded
constexpr int H1S = 136;          // h1 rows: 128 co
constexpr int H2S = 72;           // h2 rows: 64 co
// weight fragment buffer: 24 (L1: 8m x 3ks) + 16 (L2: 4m x 4ks) + 8 (L3: 4m x 2ks)
constexpr int NFRAG = 48;
constexpr int FRAG_SHORTS = NFRAG * 128 * 8;   // per frag: 64 lanes x (hi8 + lo8)

// round-to-nearest-even split: f = hi_bf16 + lo_bf16 (+O(2^-17 rel))
__device__ __forceinline__ void bf16split(float f, short &hi, short &lo) {
    unsigned u  = __builtin_bit_cast(unsigned, f);
    unsigned hb = (u + 0x7FFFu + ((u >> 16) & 1u)) & 0xFFFF0000u;
    float hf    = __builtin_bit_cast(float, hb);
    hi = (short)(hb >> 16);
    float lf    = f - hf;                       // exact
    unsigned ul = __builtin_bit_cast(unsigned, lf);
    lo = (short)((ul + 0x7FFFu + ((ul >> 16) & 1u)) >> 16);
}

__device__ __forceinline__ f32x4 mm(short8 a, short8 b, f32x4 c) {
    return __builtin_amdgcn_mfma_f32_16x16x32_bf16(a, b, c, 0, 0, 0);
}

// ---------------- prologue: BN-fold + split weights into A-fragment layout ----
__global__ void prep_wfrags(const float* __restrict__ W1, const float* __restrict__ g1,
                            const float* __restrict__ W2, const float* __restrict__ g2,
                            const float* __restrict__ W3, const float* __restrict__ g3,
                            unsigned short* __restrict__ wf)
{
    const int gid = blockIdx.x * 256 + threadIdx.x;   // [0, 3072)
    if (gid >= NFRAG * 64) return;
    const int f = gid >> 6, l = gid & 63;
    const float RS = 1.0f / sqrtf(1.0f + 1e-5f);
    const float *W, *g; int CI, m, ks;
    if (f < 24)      { W = W1; g = g1; CI = 68;  m = f / 3;        ks = f % 3; }
    else if (f < 40) { W = W2; g = g2; CI = 128; m = (f - 24) / 4; ks = (f - 24) % 4; }
    else             { W = W3; g = g3; CI = 64;  m = (f - 40) / 2; ks = (f - 40) % 2; }
    const int co = m * 16 + (l & 15);
    const int kb = ks * 32 + ((l >> 4) << 3);
    const float gs = g[co] * RS;
    short8 h8, l8;
#pragma unroll
    for (int j = 0; j < 8; ++j) {
        const int k = kb + j;
        const float w = (k < CI) ? W[(size_t)co * CI + k] * gs : 0.0f;
        short hi, lo; bf16split(w, hi, lo);
        h8[j] = hi; l8[j] = lo;
    }
    *reinterpret_cast<short8*>(wf + (size_t)(f * 128 + l) * 8)      = h8;
    *reinterpret_cast<short8*>(wf + (size_t)(f * 128 + 64 + l) * 8) = l8;
}

__device__ __forceinline__ void ldfrag(const unsigned short* __restrict__ wf,
                                       int f, int l, short8 &h, short8 &lo) {
    h  = *reinterpret_cast<const short8*>(wf + (size_t)(f * 128 + l) * 8);
    lo = *reinterpret_cast<const short8*>(wf + (size_t)(f * 128 + 64 + l) * 8);
}

__global__ __launch_bounds__(BLOCK, 4)
void mvp_mfma(const float* __restrict__ src, const float* __restrict__ tgt,
              const float* __restrict__ feat,
              const unsigned short* __restrict__ wf,
              const float* __restrict__ b1, const float* __restrict__ g1, const float* __restrict__ be1,
              const float* __restrict__ b2, const float* __restrict__ g2, const float* __restrict__ be2,
              const float* __restrict__ b3, const float* __restrict__ g3, const float* __restrict__ be3,
              float* __restrict__ out)
{
    __shared__ __align__(16) unsigned short xa_hi[96*XS],  xa_lo[96*XS];
    __shared__ __align__(16) unsigned short h1_hi[96*H1S], h1_lo[96*H1S];
    __shared__ __align__(16) unsigned short h2_hi[96*H2S], h2_lo[96*H2S];
    __shared__ float bias1[128], bias2[64], bias3[64];

    const int tid = threadIdx.x;
    const int w   = tid >> 6;
    const int l   = tid & 63;
    const int b   = blockIdx.x >> 10;
    const int n0  = (blockIdx.x & 1023) * P_;
    const float RS = 1.0f / sqrtf(1.0f + 1e-5f);

    // ================= staging =================
    for (int idx = tid; idx < 96 * 8; idx += BLOCK) {       // zero xa pad ci 68..99
        const int col = idx >> 3, ch = idx & 7;
        *reinterpret_cast<short4v*>(&xa_hi[col*XS + 68 + ch*4]) = short4v{0,0,0,0};
        *reinterpret_cast<short4v*>(&xa_lo[col*XS + 68 + ch*4]) = short4v{0,0,0,0};
    }
    for (int idx = tid; idx < C_ * P_; idx += BLOCK) {      // feature -> ci 0..63
        const int c = idx >> 5, p = idx & 31;
        const float4 f = *reinterpret_cast<const float4*>(
            feat + ((size_t)(b*C_ + c) * N_ + (n0 + p)) * K_);
        const float v[3] = {f.x, f.y, f.z};
#pragma unroll
        for (int k = 0; k < 3; ++k) {
            short hi, lo; bf16split(v[k], hi, lo);
            const int off = (k*32 + p) * XS + c;
            xa_hi[off] = (unsigned short)hi; xa_lo[off] = (unsigned short)lo;
        }
    }
    if (tid < 96) {                                          // relation -> ci 64..67
        const int p = tid & 31, k = tid >> 5;
        const int n = n0 + p;
        float d[4];
        d[0] = src[((size_t)(b*3+0)*N_ + n)*K_ + k] - tgt[(size_t)(b*3+0)*N_ + n];
        d[1] = src[((size_t)(b*3+1)*N_ + n)*K_ + k] - tgt[(size_t)(b*3+1)*N_ + n];
        d[2] = src[((size_t)(b*3+2)*N_ + n)*K_ + k] - tgt[(size_t)(b*3+2)*N_ + n];
        d[3] = d[0]*d[0] + d[1]*d[1] + d[2]*d[2];
        const int col = k*32 + p;
#pragma unroll
        for (int j = 0; j < 4; ++j) {
            short hi, lo; bf16split(d[j], hi, lo);
            xa_hi[col*XS + 64 + j] = (unsigned short)hi;
            xa_lo[col*XS + 64 + j] = (unsigned short)lo;
        }
    }
    if (tid >= 256 && tid < 384) { int c = tid - 256; bias1[c] = b1[c]*(g1[c]*RS) + be1[c]; }
    if (tid >= 384 && tid < 448) { int c = tid - 384; bias2[c] = b2[c]*(g2[c]*RS) + be2[c]; }
    if (tid >= 448 && tid < 512) { int c = tid - 448; bias3[c] = b3[c]*(g3[c]*RS) + be3[c]; }
    __syncthreads();

    const int kq = (l >> 4) << 3;   // fragment k-offset: 0,8,16,24
    const int lr = l & 15;
    const int rq = (l >> 4) << 2;   // C/D row offset

    // ================= L1: 68 -> 128 =================
    {
        const int m = w >> 1, hh = w & 1;
        short8 ah[3], al[3];
#pragma unroll
        for (int ks = 0; ks < 3; ++ks) ldfrag(wf, m*3 + ks, l, ah[ks], al[ks]);
        f32x4 acc[3] = {f32x4{0,0,0,0}, f32x4{0,0,0,0}, f32x4{0,0,0,0}};
#pragma unroll
        for (int ks = 0; ks < 3; ++ks) {
#pragma unroll
            for (int t = 0; t < 3; ++t) {
                const int col = (2*t + hh)*16 + lr;
                const short8 bh = *reinterpret_cast<const short8*>(&xa_hi[col*XS + ks*32 + kq]);
                const short8 bl = *reinterpret_cast<const short8*>(&xa_lo[col*XS + ks*32 + kq]);
                acc[t] = mm(ah[ks], bh, acc[t]);
                acc[t] = mm(al[ks], bh, acc[t]);
                acc[t] = mm(ah[ks], bl, acc[t]);
            }
        }
        const int co0 = m*16 + rq;
        const float4 bb = *reinterpret_cast<const float4*>(&bias1[co0]);
        const float bbv[4] = {bb.x, bb.y, bb.z, bb.w};
#pragma unroll
        for (int t = 0; t < 3; ++t) {
            const int col = (2*t + hh)*16 + lr;
            short4v h4, l4;
#pragma unroll
            for (int r = 0; r < 4; ++r) {
                const float v = fmaxf(acc[t][r] + bbv[r], 0.0f);
                short hi, lo; bf16split(v, hi, lo);
                h4[r] = hi; l4[r] = lo;
            }
            *reinterpret_cast<short4v*>(&h1_hi[col*H1S + co0]) = h4;
            *reinterpret_cast<short4v*>(&h1_lo[col*H1S + co0]) = l4;
        }
    }
    __syncthreads();

    // ================= L2: 128 -> 64 =================
    {
        const int ntile = (w < 8) ? 2 : 1;
        for (int tt = 0; tt < ntile; ++tt) {
            const int t = w + tt*16;               // 0..23
            const int m = t / 6, n = t % 6;
            const int col = n*16 + lr;
            f32x4 acc = {0,0,0,0};
#pragma unroll
            for (int ks = 0; ks < 4; ++ks) {
                short8 ah, al;
                ldfrag(wf, 24 + m*4 + ks, l, ah, al);
                const short8 bh = *reinterpret_cast<const short8*>(&h1_hi[col*H1S + ks*32 + kq]);
                const short8 bl = *reinterpret_cast<const short8*>(&h1_lo[col*H1S + ks*32 + kq]);
                acc = mm(ah, bh, acc);
                acc = mm(al, bh, acc);
                acc = mm(ah, bl, acc);
            }
            const int co0 = m*16 + rq;
            const float4 bb = *reinterpret_cast<const float4*>(&bias2[co0]);
            const float bbv[4] = {bb.x, bb.y, bb.z, bb.w};
            short4v h4, l4;
#pragma unroll
            for (int r = 0; r < 4; ++r) {
                const float v = fmaxf(acc[r] + bbv[r], 0.0f);
                short hi, lo; bf16split(v, hi, lo);
                h4[r] = hi; l4[r] = lo;
            }
            *reinterpret_cast<short4v*>(&h2_hi[col*H2S + co0]) = h4;
            *reinterpret_cast<short4v*>(&h2_lo[col*H2S + co0]) = l4;
        }
    }
    __syncthreads();

    // ================= L3: 64 -> 64, relu + neighbor-sum + store =================
    if (w < 8) {
        const int m = w >> 1, hh = w & 1;
        short8 ah[2], al[2];
#pragma unroll
        for (int ks = 0; ks < 2; ++ks) ldfrag(wf, 40 + m*2 + ks, l, ah[ks], al[ks]);
        f32x4 acc[3] = {f32x4{0,0,0,0}, f32x4{0,0,0,0}, f32x4{0,0,0,0}};
#pragma unroll
        for (int ks = 0; ks < 2; ++ks) {
#pragma unroll
            for (int t = 0; t < 3; ++t) {          // t = neighbor k; col = k*32 + p
                const int col = t*32 + hh*16 + lr;
                const short8 bh = *reinterpret_cast<const short8*>(&h2_hi[col*H2S + ks*32 + kq]);
                const short8 bl = *reinterpret_cast<const short8*>(&h2_lo[col*H2S + ks*32 + kq]);
                acc[t] = mm(ah[ks], bh, acc[t]);
                acc[t] = mm(al[ks], bh, acc[t]);
                acc[t] = mm(ah[ks], bl, acc[t]);
            }
        }
        const int co0 = m*16 + rq;
        const float4 bb = *reinterpret_cast<const float4*>(&bias3[co0]);
        const float bbv[4] = {bb.x, bb.y, bb.z, bb.w};
        const int p = hh*16 + lr;
#pragma unroll
        for (int r = 0; r < 4; ++r) {
            float s = 0.0f;
#pragma unroll
            for (int t = 0; t < 3; ++t) s += fmaxf(acc[t][r] + bbv[r], 0.0f);
            out[(size_t)(b*64 + co0 + r) * N_ + n0 + p] = s;
        }
    }
}

extern "C" void kernel_launch(void* const* d_in, const int* in_sizes, int n_in,
                              void* d_out, int out_size, void* d_ws, size_t ws_size,
                              hipStream_t stream) {
    const float* src  = (const float*)d_in[0];
    const float* tgt  = (const float*)d_in[1];
    const float* feat = (const float*)d_in[2];
    const float* W1 = (const float*)d_in[3];
    const float* b1 = (const float*)d_in[4];
    const float* g1 = (const float*)d_in[5];
    const float* be1= (const float*)d_in[6];
    const float* W2 = (const float*)d_in[7];
    const float* b2 = (const float*)d_in[8];
    const float* g2 = (const float*)d_in[9];
    const float* be2= (const float*)d_in[10];
    const float* W3 = (const float*)d_in[11];
    const float* b3 = (const float*)d_in[12];
    const float* g3 = (const float*)d_in[13];
    const float* be3= (const float*)d_in[14];
    float* out = (float*)d_out;
    unsigned short* wfrag = (unsigned short*)d_ws;   // 96 KB

    prep_wfrags<<<(NFRAG*64 + 255)/256, 256, 0, stream>>>(W1, g1, W2, g2, W3, g3, wfrag);

    const int grid = B_ * (N_ / P_);  // 4096
    mvp_mfma<<<grid, BLOCK, 0, stream>>>(src, tgt, feat, wfrag,
                                         b1, g1, be1, b2, g2, be2, b3, g3, be3, out);
}